// Round 11
// baseline (4535.424 us; speedup 1.0000x reference)
//
#include <hip/hip_runtime.h>
#include <hip/hip_bf16.h>

typedef __attribute__((ext_vector_type(8))) short short8;
typedef __attribute__((ext_vector_type(4))) float f32x4;
typedef unsigned long long u64;

#define V_N 10000
#define D_E 128
#define H_N 512
#define B_N 32
#define S_N 512

#define SENT64 0xFFFFFFFFFFFFFFFFull   // 4x bf16 NaN: unreachable for finite h

// ---- workspace layout (bytes) ----
#define OFF_RP    0                        // rowpart: 16384 rows x 80 slots f32 = 5,242,880
#define OFF_EMB   5242880                  // S*B*D bf16 = 4,194,304
#define OFF_HS    (OFF_EMB + 4194304)      // S*B*H bf16 = 16,777,216
#define OFF_WOUT  (OFF_HS + 16777216)      // V*H bf16 = 10,240,000

// ------------------------------------------------------------------
__device__ __forceinline__ float ftanh(float x) {
  float e = __expf(-2.f * fabsf(x));          // in (0,1], overflow-safe
  float r = (1.f - e) / (1.f + e);
  return __builtin_copysignf(r, x);
}

union U128 { f32x4 f; u64 q[2]; };

// ------------------------------------------------------------------
// prep: embedding gather -> bf16 [s][b][d]
__global__ void k_prep_emb(const int* __restrict__ x, const float* __restrict__ tab,
                           __hip_bfloat16* __restrict__ emb) {
  int i = blockIdx.x * 256 + threadIdx.x;         // over S*B*D = 2,097,152
  if (i >= S_N * B_N * D_E) return;
  int d  = i & (D_E - 1);
  int sb = i >> 7;
  int b  = sb & (B_N - 1);
  int s  = sb >> 5;
  int tok = x[b * S_N + s];
  emb[i] = __float2bfloat16(tab[tok * D_E + d]);
}

// prep: W_out -> bf16
__global__ void k_prep_wout(const float* __restrict__ w, __hip_bfloat16* __restrict__ o) {
  int i = blockIdx.x * 256 + threadIdx.x;
  if (i < V_N * H_N) o[i] = __float2bfloat16(w[i]);
}

// ------------------------------------------------------------------
// persistent recurrence: 16 WGs x 1024 threads. WG w owns h-dims
// j = 32w..32w+31 (256 gate rows). 16 waves = 8 row-groups x 2 K-slices(320).
// A (weights) in registers (80 VGPR/lane, same as before); B staged in LDS.
// Cross-WG exchange: write-once sentinel slots in hs[t]; consumers poll the
// data itself with 16-B bypass loads (2 chunks/thread); publish is
// fire-and-forget. 4x less poll traffic than the 64-WG version.
__launch_bounds__(1024, 1)
__global__ void k_recurrence(const int* __restrict__ x,
                             const float* __restrict__ W_ih, const float* __restrict__ W_hh,
                             const float* __restrict__ b_ih, const float* __restrict__ b_hh,
                             const __hip_bfloat16* __restrict__ emb,
                             __hip_bfloat16* __restrict__ hs)     // [512][32][512]
{
  __shared__ __align__(16) __hip_bfloat16 Bl[32][648];  // [example][emb128 ; h512]
  __shared__ float gl[2][256][33];         // [K-slice][gate row][example] partials
  __shared__ float bias[256];
  __shared__ unsigned short hloc[32][32];  // [jj][ex] bf16 bits of new h

  const int tid = threadIdx.x;
  const int wg  = blockIdx.x;              // 0..15
  const int lane = tid & 63, wv = tid >> 6;       // wv = wave 0..15
  const int rg  = wv >> 1, ks2 = wv & 1;          // row-group, K-slice
  const int lrow = lane & 15, lk = (lane >> 4) * 8;
  const int b_ep = tid & 31, jj_ep = tid >> 5;    // epilogue map: 32 ex x 32 dims

  // ---- one-time: A-fragments (32 rows x K-slice 320) into registers ----
  short8 Afrag[20];                        // [mt*10+ks], 80 VGPRs
  #pragma unroll
  for (int mt = 0; mt < 2; ++mt) {
    #pragma unroll
    for (int ks = 0; ks < 10; ++ks) {
      int lr = rg * 32 + mt * 16 + lrow;   // local gate row 0..255
      int q = lr >> 6, kc = (lr >> 5) & 1, jj = lr & 31;
      int grow = kc * 2048 + q * 512 + wg * 32 + jj;
      int c0 = ks2 * 320 + ks * 32 + lk;
      short8 a;
      #pragma unroll
      for (int e = 0; e < 8; ++e) {
        int c = c0 + e;
        float v = (c < 128) ? W_ih[(size_t)grow * 128 + c]
                            : W_hh[(size_t)grow * 512 + (c - 128)];
        __hip_bfloat16 hb = __float2bfloat16(v);
        a[e] = *(const short*)&hb;
      }
      Afrag[mt * 10 + ks] = a;
    }
  }
  if (tid < 256) {
    int lr = tid;
    int q = lr >> 6, kc = (lr >> 5) & 1, jj = lr & 31;
    int grow = kc * 2048 + q * 512 + wg * 32 + jj;
    bias[lr] = b_ih[grow] + b_hh[grow];
  }

  // ---- preload token parity bits (b_ep's row of x) ----
  unsigned par[16];
  #pragma unroll
  for (int w = 0; w < 16; ++w) {
    unsigned p = 0;
    for (int bb = 0; bb < 32; ++bb)
      p |= (unsigned)(x[b_ep * S_N + w * 32 + bb] & 1) << bb;
    par[w] = p;
  }

  float c_state = 0.f;                         // carry for (b_ep, jj_ep)

  for (int t = 0; t < S_N; ++t) {
    // ---- stage emb_t: 512 x 16B cached loads (tid<512) ----
    if (tid < 512) {
      const f32x4* e16 = (const f32x4*)(emb + (size_t)t * B_N * D_E);
      int ex = tid >> 4, col = tid & 15;
      *(f32x4*)((char*)&Bl[0][0] + ex * 1296 + col * 16) = e16[tid];
    }
    // ---- stage h_prev: masked 16-B sentinel poll, 2 chunks/thread ----
    if (t == 0) {
      for (int i = tid; i < 4096; i += 1024) {
        int b = i >> 7, hh = i & 127;
        *(u64*)&Bl[b][128 + hh * 4] = 0ull;
      }
    } else {
      const char* srcb = (const char*)hs + (size_t)(t - 1) * 32768;
      U128 buf[2];
      unsigned pend = 3u;
      while (pend) {
        #pragma unroll
        for (int c = 0; c < 2; ++c)
          if (pend & (1u << c))
            asm volatile("global_load_dwordx4 %0, %1, off sc0 sc1"
                         : "=v"(buf[c].f) : "v"(srcb + (c * 16384 + tid * 16)) : "memory");
        asm volatile("s_waitcnt vmcnt(0)" ::: "memory");
        __builtin_amdgcn_sched_barrier(0);
        #pragma unroll
        for (int c = 0; c < 2; ++c)
          if ((pend & (1u << c)) && buf[c].q[0] != SENT64 && buf[c].q[1] != SENT64) {
            int ci = c * 1024 + tid;       // chunk 0..2047
            *(f32x4*)((char*)&Bl[0][0] + (ci >> 6) * 1296 + 256 + (ci & 63) * 16) = buf[c].f;
            pend &= ~(1u << c);
          }
      }
    }
    __syncthreads();                 // A: B ready

    // ---- MFMA: wave (rg,ks2): rows [rg*32,+32) x 32 ex over K-slice 320 ----
    {
      f32x4 acc[2][2] = {};
      #pragma unroll
      for (int ks = 0; ks < 10; ++ks) {
        int cb = (ks2 * 320 + ks * 32 + lk) * 2;   // byte offset in a row
        short8 b0 = *(const short8*)((const char*)&Bl[0][0] + lrow * 1296 + cb);
        short8 b1 = *(const short8*)((const char*)&Bl[0][0] + (16 + lrow) * 1296 + cb);
        #pragma unroll
        for (int mt = 0; mt < 2; ++mt) {
          acc[mt][0] = __builtin_amdgcn_mfma_f32_16x16x32_bf16(Afrag[mt * 10 + ks], b0, acc[mt][0], 0, 0, 0);
          acc[mt][1] = __builtin_amdgcn_mfma_f32_16x16x32_bf16(Afrag[mt * 10 + ks], b1, acc[mt][1], 0, 0, 0);
        }
      }
      #pragma unroll
      for (int mt = 0; mt < 2; ++mt)
        #pragma unroll
        for (int nt = 0; nt < 2; ++nt)
          #pragma unroll
          for (int r = 0; r < 4; ++r)
            gl[ks2][rg * 32 + mt * 16 + (lane >> 4) * 4 + r][nt * 16 + (lane & 15)] = acc[mt][nt][r];
    }
    __syncthreads();                 // B: both K-slice partials ready

    // ---- epilogue: thread <-> (b_ep, jj_ep); sum 2 K-partials ----
    {
      float cand_c[2], cand_h[2];
      #pragma unroll
      for (int kc = 0; kc < 2; ++kc) {
        int base = kc * 32 + jj_ep;
        float ig = gl[0][base][b_ep]       + gl[1][base][b_ep]       + bias[base];
        float fg = gl[0][64 + base][b_ep]  + gl[1][64 + base][b_ep]  + bias[64 + base];
        float gg = gl[0][128 + base][b_ep] + gl[1][128 + base][b_ep] + bias[128 + base];
        float og = gl[0][192 + base][b_ep] + gl[1][192 + base][b_ep] + bias[192 + base];
        ig = 1.f / (1.f + __expf(-ig));
        fg = 1.f / (1.f + __expf(-fg));
        og = 1.f / (1.f + __expf(-og));
        gg = ftanh(gg);
        float cn = fg * c_state + ig * gg;
        cand_c[kc] = cn;
        cand_h[kc] = og * ftanh(cn);
      }
      int sel = (par[t >> 5] >> (t & 31)) & 1;
      c_state  = sel ? cand_c[1] : cand_c[0];
      float hv = sel ? cand_h[1] : cand_h[0];
      __hip_bfloat16 hb = __float2bfloat16(hv);
      hloc[jj_ep][b_ep] = *(const unsigned short*)&hb;
    }
    __syncthreads();                 // C: hloc complete; Bl/gl free next step

    // ---- publish h(t) into hs[t]: fire-and-forget bypass stores ----
    if (tid < 256) {                 // 32 ex x 8 u64 (=32 dims) per WG
      int ex = tid >> 3, part = tid & 7;
      u64 v = (u64)hloc[part * 4 + 0][ex]
            | ((u64)hloc[part * 4 + 1][ex] << 16)
            | ((u64)hloc[part * 4 + 2][ex] << 32)
            | ((u64)hloc[part * 4 + 3][ex] << 48);
      u64* dst = (u64*)hs + (size_t)t * 4096 + ex * 128 + wg * 8 + part;
      __hip_atomic_store(dst, v, __ATOMIC_RELAXED, __HIP_MEMORY_SCOPE_AGENT);
    }
    // no wait, no flag: consumers poll the data itself
  }
}

// ------------------------------------------------------------------
// logits GEMM: M=16384 (=S*B), N=10000, K=512, bf16 MFMA, +bias.
// Deterministic fused softmax-denominator: per-block per-row partial
// sum(exp(logit)) -> unique slot rowpart[row][tn] (NO atomics).
__launch_bounds__(256, 2)
__global__ void k_gemm(const __hip_bfloat16* __restrict__ hs,
                       const __hip_bfloat16* __restrict__ wout,
                       const float* __restrict__ b_out,
                       float* __restrict__ out,
                       float* __restrict__ rowpart)   // [16384][80]
{
  __shared__ __hip_bfloat16 Al[128][72];
  __shared__ __hip_bfloat16 Wt[128][72];
  __shared__ float sumLDS[2][128];         // [nq][row_local]
  const int tid = threadIdx.x;
  const int tn = blockIdx.x, tm = blockIdx.y;
  const int lane = tid & 63, wv = tid >> 6;
  const int mq = wv & 1, nq = wv >> 1;
  const int lrow = lane & 15, lk = (lane >> 4) * 8;
  f32x4 acc[4][4] = {};

  const int ar = tid >> 3, ac = (tid & 7) * 8;
  for (int k0 = 0; k0 < 512; k0 += 64) {
    __syncthreads();
    #pragma unroll
    for (int rr = 0; rr < 4; ++rr) {
      int r = ar + rr * 32;
      short8 av = *(const short8*)(hs + ((size_t)(tm * 128 + r)) * 512 + k0 + ac);
      *(short8*)&Al[r][ac] = av;
      int v = tn * 128 + r;
      short8 wvv = {};
      if (v < V_N) wvv = *(const short8*)(wout + (size_t)v * 512 + k0 + ac);
      *(short8*)&Wt[r][ac] = wvv;
    }
    __syncthreads();
    #pragma unroll
    for (int ks = 0; ks < 2; ++ks) {
      int kb = ks * 32 + lk;
      short8 af[4], bf[4];
      #pragma unroll
      for (int i = 0; i < 4; ++i) af[i] = *(const short8*)&Al[mq * 64 + i * 16 + lrow][kb];
      #pragma unroll
      for (int i = 0; i < 4; ++i) bf[i] = *(const short8*)&Wt[nq * 64 + i * 16 + lrow][kb];
      #pragma unroll
      for (int i = 0; i < 4; ++i)
        #pragma unroll
        for (int jx = 0; jx < 4; ++jx)
          acc[i][jx] = __builtin_amdgcn_mfma_f32_16x16x32_bf16(af[i], bf[jx], acc[i][jx], 0, 0, 0);
    }
  }
  const int rbase = tm * 128 + mq * 64 + (lane >> 4) * 4;
  const int cbase = tn * 128 + nq * 64 + (lane & 15);
  float esum[4][4];
  #pragma unroll
  for (int i = 0; i < 4; ++i)
    #pragma unroll
    for (int r = 0; r < 4; ++r) esum[i][r] = 0.f;

  #pragma unroll
  for (int i = 0; i < 4; ++i) {
    #pragma unroll
    for (int jx = 0; jx < 4; ++jx) {
      int col = cbase + jx * 16;
      if (col < V_N) {
        float bo = b_out[col];
        #pragma unroll
        for (int r = 0; r < 4; ++r) {
          int row = rbase + i * 16 + r;
          float lg = acc[i][jx][r] + bo;
          out[(size_t)row * V_N + col] = lg;
          esum[i][r] += __expf(lg);
        }
      }
    }
  }
  // reduce each (i,r) over the 16 lanes of the col group; write LDS partial
  #pragma unroll
  for (int i = 0; i < 4; ++i) {
    #pragma unroll
    for (int r = 0; r < 4; ++r) {
      float s = esum[i][r];
      s += __shfl_xor(s, 1); s += __shfl_xor(s, 2);
      s += __shfl_xor(s, 4); s += __shfl_xor(s, 8);
      if ((lane & 15) == 0)
        sumLDS[nq][mq * 64 + i * 16 + (lane >> 4) * 4 + r] = s;
    }
  }
  __syncthreads();
  if (tid < 128)   // one plain store per (row, tile): deterministic slot
    rowpart[(size_t)(tm * 128 + tid) * 80 + tn] = sumLDS[0][tid] + sumLDS[1][tid];
}

// ------------------------------------------------------------------
// fix-up: lse[r] = log(sum of 79 partials, fixed order); out[r][:] -= lse
__launch_bounds__(256)
__global__ void k_lsm_fix(float* __restrict__ out, const float* __restrict__ rowpart) {
  const int r = blockIdx.x;
  const float* rp = rowpart + (size_t)r * 80;
  float s = 0.f;
  for (int p = 0; p < 79; ++p) s += rp[p];   // same order in every thread/replay
  float lse = __logf(s);
  float4* q4 = (float4*)(out + (size_t)r * V_N);
  for (int i = threadIdx.x; i < V_N / 4; i += 256) {
    float4 v = q4[i];
    v.x -= lse; v.y -= lse; v.z -= lse; v.w -= lse;
    q4[i] = v;
  }
}

// ------------------------------------------------------------------
extern "C" void kernel_launch(void* const* d_in, const int* in_sizes, int n_in,
                              void* d_out, int out_size, void* d_ws, size_t ws_size,
                              hipStream_t stream) {
  const int*   x    = (const int*)d_in[0];
  const float* tab  = (const float*)d_in[1];
  const float* Wih  = (const float*)d_in[2];
  const float* Whh  = (const float*)d_in[3];
  const float* bih  = (const float*)d_in[4];
  const float* bhh  = (const float*)d_in[5];
  const float* Wout = (const float*)d_in[6];
  const float* bout = (const float*)d_in[7];
  float* out = (float*)d_out;

  char* ws = (char*)d_ws;
  float*           rowpart = (float*)(ws + OFF_RP);
  __hip_bfloat16*  emb     = (__hip_bfloat16*)(ws + OFF_EMB);
  __hip_bfloat16*  hsbuf   = (__hip_bfloat16*)(ws + OFF_HS);
  __hip_bfloat16*  wob     = (__hip_bfloat16*)(ws + OFF_WOUT);

  // re-poison hs to the write-once sentinel every launch (replay-safe)
  hipMemsetAsync(hsbuf, 0xFF, (size_t)S_N * B_N * H_N * 2, stream);
  k_prep_emb<<<(S_N * B_N * D_E) / 256, 256, 0, stream>>>(x, tab, emb);
  k_prep_wout<<<(V_N * H_N) / 256, 256, 0, stream>>>(Wout, wob);
  k_recurrence<<<16, 1024, 0, stream>>>(x, Wih, Whh, bih, bhh, emb, hsbuf);
  k_gemm<<<dim3(79, 128), 256, 0, stream>>>(hsbuf, wob, bout, out, rowpart);
  k_lsm_fix<<<16384, 256, 0, stream>>>(out, rowpart);
}

// Round 12
// 2456.170 us; speedup vs baseline: 1.8465x; 1.8465x over previous
//
#include <hip/hip_runtime.h>
#include <hip/hip_bf16.h>

typedef __attribute__((ext_vector_type(8))) short short8;
typedef __attribute__((ext_vector_type(4))) float f32x4;
typedef unsigned long long u64;

#define V_N 10000
#define D_E 128
#define H_N 512
#define B_N 32
#define S_N 512

#define SENT64 0xFFFFFFFFFFFFFFFFull   // 4x bf16 NaN: unreachable for finite h

// ---- workspace layout (bytes) ----
#define OFF_RP    0                        // rowpart: 16384 rows x 80 slots f32 = 5,242,880
#define OFF_EMB   5242880                  // S*B*D bf16 = 4,194,304
#define OFF_HS    (OFF_EMB + 4194304)      // S*B*H bf16 = 16,777,216
#define OFF_WOUT  (OFF_HS + 16777216)      // V*H bf16 = 10,240,000

// ------------------------------------------------------------------
__device__ __forceinline__ float ftanh(float x) {
  float e = __expf(-2.f * fabsf(x));          // in (0,1], overflow-safe
  float r = (1.f - e) / (1.f + e);
  return __builtin_copysignf(r, x);
}

union U128 { f32x4 f; u64 q[2]; };

// ------------------------------------------------------------------
// prep: embedding gather -> bf16 [s][b][d]
__global__ void k_prep_emb(const int* __restrict__ x, const float* __restrict__ tab,
                           __hip_bfloat16* __restrict__ emb) {
  int i = blockIdx.x * 256 + threadIdx.x;         // over S*B*D = 2,097,152
  if (i >= S_N * B_N * D_E) return;
  int d  = i & (D_E - 1);
  int sb = i >> 7;
  int b  = sb & (B_N - 1);
  int s  = sb >> 5;
  int tok = x[b * S_N + s];
  emb[i] = __float2bfloat16(tab[tok * D_E + d]);
}

// prep: W_out -> bf16
__global__ void k_prep_wout(const float* __restrict__ w, __hip_bfloat16* __restrict__ o) {
  int i = blockIdx.x * 256 + threadIdx.x;
  if (i < V_N * H_N) o[i] = __float2bfloat16(w[i]);
}

// ------------------------------------------------------------------
// persistent recurrence: 32 WGs x 512 threads (8 waves = 2/SIMD, 256-VGPR
// budget -> Afrag[20] fits in registers, NO spill). WG w owns h-dims
// j = 16w..16w+15 (128 gate rows). Each wave: 16 rows x 32 examples over
// FULL K=640 (no K-split -> gl written once, epilogue reads direct).
// Cross-WG exchange: write-once sentinel slots in hs[t]; consumers poll
// the data itself (4 x 16-B bypass chunks/thread, masked retry, linear
// conflict-free commit). Publish fire-and-forget. Poll traffic: 1 MB/sweep
// (half of the 64-WG version).
__launch_bounds__(512, 1)
__global__ void k_recurrence(const int* __restrict__ x,
                             const float* __restrict__ W_ih, const float* __restrict__ W_hh,
                             const float* __restrict__ b_ih, const float* __restrict__ b_hh,
                             const __hip_bfloat16* __restrict__ emb,
                             __hip_bfloat16* __restrict__ hs)     // [512][32][512]
{
  __shared__ __align__(16) __hip_bfloat16 Bl[32][648];  // [example][emb128 ; h512]
  __shared__ float gl[128][34];            // [gate row][example] full-K gates
  __shared__ float bias[128];
  __shared__ unsigned short hloc[16][32];  // [jj][ex] bf16 bits of new h

  const int tid = threadIdx.x;
  const int wg  = blockIdx.x;              // 0..31
  const int lane = tid & 63, wv = tid >> 6;       // wv = wave 0..7 = row-group
  const int lrow = lane & 15, lk = (lane >> 4) * 8;
  const int b_ep = tid & 31, jj_ep = tid >> 5;    // epilogue map: 32 ex x 16 dims

  // ---- one-time: A-fragments (16 rows x full K 640) into registers ----
  short8 Afrag[20];                        // 80 VGPRs
  #pragma unroll
  for (int ks = 0; ks < 20; ++ks) {
    int lr = wv * 16 + lrow;               // local gate row 0..127
    int q = lr >> 5, kc = (lr >> 4) & 1, jj = lr & 15;
    int grow = kc * 2048 + q * 512 + wg * 16 + jj;
    int c0 = ks * 32 + lk;
    short8 a;
    #pragma unroll
    for (int e = 0; e < 8; ++e) {
      int c = c0 + e;
      float v = (c < 128) ? W_ih[(size_t)grow * 128 + c]
                          : W_hh[(size_t)grow * 512 + (c - 128)];
      __hip_bfloat16 hb = __float2bfloat16(v);
      a[e] = *(const short*)&hb;
    }
    Afrag[ks] = a;
  }
  if (tid < 128) {
    int lr = tid;
    int q = lr >> 5, kc = (lr >> 4) & 1, jj = lr & 15;
    int grow = kc * 2048 + q * 512 + wg * 16 + jj;
    bias[lr] = b_ih[grow] + b_hh[grow];
  }

  // ---- preload token parity bits (b_ep's row of x) ----
  unsigned par[16];
  #pragma unroll
  for (int w = 0; w < 16; ++w) {
    unsigned p = 0;
    for (int bb = 0; bb < 32; ++bb)
      p |= (unsigned)(x[b_ep * S_N + w * 32 + bb] & 1) << bb;
    par[w] = p;
  }

  float c_state = 0.f;                         // carry for (b_ep, jj_ep)

  for (int t = 0; t < S_N; ++t) {
    // ---- stage emb_t: 1 x 16B cached load/thread (512 chunks) ----
    {
      const f32x4* e16 = (const f32x4*)(emb + (size_t)t * B_N * D_E);
      int ex = tid >> 4, col = tid & 15;
      *(f32x4*)((char*)&Bl[0][0] + ex * 1296 + col * 16) = e16[tid];
    }
    // ---- stage h_prev: masked 16-B sentinel poll, 4 chunks/thread ----
    if (t == 0) {
      for (int i = tid; i < 4096; i += 512) {
        int b = i >> 7, hh = i & 127;
        *(u64*)&Bl[b][128 + hh * 4] = 0ull;
      }
    } else {
      const char* srcb = (const char*)hs + (size_t)(t - 1) * 32768;
      U128 buf[4];
      unsigned pend = 0xFu;
      while (pend) {
        #pragma unroll
        for (int c = 0; c < 4; ++c)
          if (pend & (1u << c))
            asm volatile("global_load_dwordx4 %0, %1, off sc0 sc1"
                         : "=v"(buf[c].f) : "v"(srcb + (c * 8192 + tid * 16)) : "memory");
        asm volatile("s_waitcnt vmcnt(0)" ::: "memory");
        __builtin_amdgcn_sched_barrier(0);
        #pragma unroll
        for (int c = 0; c < 4; ++c)
          if ((pend & (1u << c)) && buf[c].q[0] != SENT64 && buf[c].q[1] != SENT64) {
            int ci = c * 512 + tid;        // chunk 0..2047
            *(f32x4*)((char*)&Bl[0][0] + (ci >> 6) * 1296 + 256 + (ci & 63) * 16) = buf[c].f;
            pend &= ~(1u << c);
          }
      }
    }
    __syncthreads();                 // A: B ready

    // ---- MFMA: wave wv: rows [wv*16,+16) x 32 ex over full K=640 ----
    {
      f32x4 acc0 = {0.f,0.f,0.f,0.f}, acc1 = {0.f,0.f,0.f,0.f};
      #pragma unroll
      for (int ks = 0; ks < 20; ++ks) {
        int cb = (ks * 32 + lk) * 2;       // byte offset in a row
        short8 b0 = *(const short8*)((const char*)&Bl[0][0] + lrow * 1296 + cb);
        short8 b1 = *(const short8*)((const char*)&Bl[0][0] + (16 + lrow) * 1296 + cb);
        acc0 = __builtin_amdgcn_mfma_f32_16x16x32_bf16(Afrag[ks], b0, acc0, 0, 0, 0);
        acc1 = __builtin_amdgcn_mfma_f32_16x16x32_bf16(Afrag[ks], b1, acc1, 0, 0, 0);
      }
      int r0 = wv * 16 + (lane >> 4) * 4;
      int cb0 = lane & 15;
      #pragma unroll
      for (int r = 0; r < 4; ++r) {
        gl[r0 + r][cb0]      = acc0[r];
        gl[r0 + r][16 + cb0] = acc1[r];
      }
    }
    __syncthreads();                 // B: all gates ready (full K, no partials)

    // ---- epilogue: thread <-> (b_ep, jj_ep in 0..15) ----
    {
      float cand_c[2], cand_h[2];
      #pragma unroll
      for (int kc = 0; kc < 2; ++kc) {
        int base = kc * 16 + jj_ep;
        float ig = gl[base][b_ep]      + bias[base];
        float fg = gl[32 + base][b_ep] + bias[32 + base];
        float gg = gl[64 + base][b_ep] + bias[64 + base];
        float og = gl[96 + base][b_ep] + bias[96 + base];
        ig = 1.f / (1.f + __expf(-ig));
        fg = 1.f / (1.f + __expf(-fg));
        og = 1.f / (1.f + __expf(-og));
        gg = ftanh(gg);
        float cn = fg * c_state + ig * gg;
        cand_c[kc] = cn;
        cand_h[kc] = og * ftanh(cn);
      }
      int sel = (par[t >> 5] >> (t & 31)) & 1;
      c_state  = sel ? cand_c[1] : cand_c[0];
      float hv = sel ? cand_h[1] : cand_h[0];
      __hip_bfloat16 hb = __float2bfloat16(hv);
      hloc[jj_ep][b_ep] = *(const unsigned short*)&hb;
    }
    __syncthreads();                 // C: hloc complete; Bl/gl free next step

    // ---- publish h(t) into hs[t]: fire-and-forget bypass stores ----
    if (tid < 128) {                 // 32 ex x 4 u64 (=16 dims) per WG
      int ex = tid >> 2, part = tid & 3;
      u64 v = (u64)hloc[part * 4 + 0][ex]
            | ((u64)hloc[part * 4 + 1][ex] << 16)
            | ((u64)hloc[part * 4 + 2][ex] << 32)
            | ((u64)hloc[part * 4 + 3][ex] << 48);
      u64* dst = (u64*)hs + (size_t)t * 4096 + ex * 128 + wg * 4 + part;
      __hip_atomic_store(dst, v, __ATOMIC_RELAXED, __HIP_MEMORY_SCOPE_AGENT);
    }
    // no wait, no flag: consumers poll the data itself
  }
}

// ------------------------------------------------------------------
// logits GEMM: M=16384 (=S*B), N=10000, K=512, bf16 MFMA, +bias.
// Deterministic fused softmax-denominator: per-block per-row partial
// sum(exp(logit)) -> unique slot rowpart[row][tn] (NO atomics).
__launch_bounds__(256, 2)
__global__ void k_gemm(const __hip_bfloat16* __restrict__ hs,
                       const __hip_bfloat16* __restrict__ wout,
                       const float* __restrict__ b_out,
                       float* __restrict__ out,
                       float* __restrict__ rowpart)   // [16384][80]
{
  __shared__ __hip_bfloat16 Al[128][72];
  __shared__ __hip_bfloat16 Wt[128][72];
  __shared__ float sumLDS[2][128];         // [nq][row_local]
  const int tid = threadIdx.x;
  const int tn = blockIdx.x, tm = blockIdx.y;
  const int lane = tid & 63, wv = tid >> 6;
  const int mq = wv & 1, nq = wv >> 1;
  const int lrow = lane & 15, lk = (lane >> 4) * 8;
  f32x4 acc[4][4] = {};

  const int ar = tid >> 3, ac = (tid & 7) * 8;
  for (int k0 = 0; k0 < 512; k0 += 64) {
    __syncthreads();
    #pragma unroll
    for (int rr = 0; rr < 4; ++rr) {
      int r = ar + rr * 32;
      short8 av = *(const short8*)(hs + ((size_t)(tm * 128 + r)) * 512 + k0 + ac);
      *(short8*)&Al[r][ac] = av;
      int v = tn * 128 + r;
      short8 wvv = {};
      if (v < V_N) wvv = *(const short8*)(wout + (size_t)v * 512 + k0 + ac);
      *(short8*)&Wt[r][ac] = wvv;
    }
    __syncthreads();
    #pragma unroll
    for (int ks = 0; ks < 2; ++ks) {
      int kb = ks * 32 + lk;
      short8 af[4], bf[4];
      #pragma unroll
      for (int i = 0; i < 4; ++i) af[i] = *(const short8*)&Al[mq * 64 + i * 16 + lrow][kb];
      #pragma unroll
      for (int i = 0; i < 4; ++i) bf[i] = *(const short8*)&Wt[nq * 64 + i * 16 + lrow][kb];
      #pragma unroll
      for (int i = 0; i < 4; ++i)
        #pragma unroll
        for (int jx = 0; jx < 4; ++jx)
          acc[i][jx] = __builtin_amdgcn_mfma_f32_16x16x32_bf16(af[i], bf[jx], acc[i][jx], 0, 0, 0);
    }
  }
  const int rbase = tm * 128 + mq * 64 + (lane >> 4) * 4;
  const int cbase = tn * 128 + nq * 64 + (lane & 15);
  float esum[4][4];
  #pragma unroll
  for (int i = 0; i < 4; ++i)
    #pragma unroll
    for (int r = 0; r < 4; ++r) esum[i][r] = 0.f;

  #pragma unroll
  for (int i = 0; i < 4; ++i) {
    #pragma unroll
    for (int jx = 0; jx < 4; ++jx) {
      int col = cbase + jx * 16;
      if (col < V_N) {
        float bo = b_out[col];
        #pragma unroll
        for (int r = 0; r < 4; ++r) {
          int row = rbase + i * 16 + r;
          float lg = acc[i][jx][r] + bo;
          out[(size_t)row * V_N + col] = lg;
          esum[i][r] += __expf(lg);
        }
      }
    }
  }
  // reduce each (i,r) over the 16 lanes of the col group; write LDS partial
  #pragma unroll
  for (int i = 0; i < 4; ++i) {
    #pragma unroll
    for (int r = 0; r < 4; ++r) {
      float s = esum[i][r];
      s += __shfl_xor(s, 1); s += __shfl_xor(s, 2);
      s += __shfl_xor(s, 4); s += __shfl_xor(s, 8);
      if ((lane & 15) == 0)
        sumLDS[nq][mq * 64 + i * 16 + (lane >> 4) * 4 + r] = s;
    }
  }
  __syncthreads();
  if (tid < 128)   // one plain store per (row, tile): deterministic slot
    rowpart[(size_t)(tm * 128 + tid) * 80 + tn] = sumLDS[0][tid] + sumLDS[1][tid];
}

// ------------------------------------------------------------------
// fix-up: lse[r] = log(sum of 79 partials, fixed order); out[r][:] -= lse
__launch_bounds__(256)
__global__ void k_lsm_fix(float* __restrict__ out, const float* __restrict__ rowpart) {
  const int r = blockIdx.x;
  const float* rp = rowpart + (size_t)r * 80;
  float s = 0.f;
  for (int p = 0; p < 79; ++p) s += rp[p];   // same order in every thread/replay
  float lse = __logf(s);
  float4* q4 = (float4*)(out + (size_t)r * V_N);
  for (int i = threadIdx.x; i < V_N / 4; i += 256) {
    float4 v = q4[i];
    v.x -= lse; v.y -= lse; v.z -= lse; v.w -= lse;
    q4[i] = v;
  }
}

// ------------------------------------------------------------------
extern "C" void kernel_launch(void* const* d_in, const int* in_sizes, int n_in,
                              void* d_out, int out_size, void* d_ws, size_t ws_size,
                              hipStream_t stream) {
  const int*   x    = (const int*)d_in[0];
  const float* tab  = (const float*)d_in[1];
  const float* Wih  = (const float*)d_in[2];
  const float* Whh  = (const float*)d_in[3];
  const float* bih  = (const float*)d_in[4];
  const float* bhh  = (const float*)d_in[5];
  const float* Wout = (const float*)d_in[6];
  const float* bout = (const float*)d_in[7];
  float* out = (float*)d_out;

  char* ws = (char*)d_ws;
  float*           rowpart = (float*)(ws + OFF_RP);
  __hip_bfloat16*  emb     = (__hip_bfloat16*)(ws + OFF_EMB);
  __hip_bfloat16*  hsbuf   = (__hip_bfloat16*)(ws + OFF_HS);
  __hip_bfloat16*  wob     = (__hip_bfloat16*)(ws + OFF_WOUT);

  // re-poison hs to the write-once sentinel every launch (replay-safe)
  hipMemsetAsync(hsbuf, 0xFF, (size_t)S_N * B_N * H_N * 2, stream);
  k_prep_emb<<<(S_N * B_N * D_E) / 256, 256, 0, stream>>>(x, tab, emb);
  k_prep_wout<<<(V_N * H_N) / 256, 256, 0, stream>>>(Wout, wob);
  k_recurrence<<<32, 512, 0, stream>>>(x, Wih, Whh, bih, bhh, emb, hsbuf);
  k_gemm<<<dim3(79, 128), 256, 0, stream>>>(hsbuf, wob, bout, out, rowpart);
  k_lsm_fix<<<16384, 256, 0, stream>>>(out, rowpart);
}